// Round 6
// baseline (365.717 us; speedup 1.0000x reference)
//
#include <hip/hip_runtime.h>
#include <cmath>

#define C_SCALE 0.18033688011112042f   // 0.125 * log2(e)

typedef __attribute__((ext_vector_type(8))) short bf16x8;
typedef __attribute__((ext_vector_type(8))) _Float16 half8;
typedef __attribute__((ext_vector_type(4))) _Float16 half4;
typedef __attribute__((ext_vector_type(4))) float f32x4;
typedef __attribute__((ext_vector_type(4))) unsigned short us4;

__device__ inline unsigned short bf16_rne(float f) {
    unsigned u = __builtin_bit_cast(unsigned, f);
    u += 0x7fff + ((u >> 16) & 1);
    return (unsigned short)(u >> 16);
}

__device__ inline void lds_dma16(const _Float16* g, _Float16* l) {
    __builtin_amdgcn_global_load_lds(
        (__attribute__((address_space(1))) void*)(void*)g,
        (__attribute__((address_space(3))) void*)(void*)l, 16, 0, 0);
}

// ---------------------------------------------------------------------------
// Fused prep: bx<1280 -> transpose W matrices fp32->fp16 (Wt[col][k]);
// bx>=1280 -> fp32->fp16 convert of x/mem/rel.
// ---------------------------------------------------------------------------
__global__ __launch_bounds__(256) void prep_kernel(
    const float* __restrict__ x, const float* __restrict__ mem,
    const float* __restrict__ rel,
    const float* __restrict__ s0, const float* __restrict__ s1,
    const float* __restrict__ s2, const float* __restrict__ s3,
    const float* __restrict__ s4,
    _Float16* __restrict__ x16, _Float16* __restrict__ mem16,
    _Float16* __restrict__ rel16,
    _Float16* __restrict__ d0, _Float16* __restrict__ d1,
    _Float16* __restrict__ d2, _Float16* __restrict__ d3,
    _Float16* __restrict__ d4)
{
    const int bx = blockIdx.x, tid = threadIdx.x;
    if (bx < 1280) {
        __shared__ _Float16 T[64][72];
        const int z = bx >> 8, rem = bx & 255;
        const float* src = z == 0 ? s0 : z == 1 ? s1 : z == 2 ? s2 : z == 3 ? s3 : s4;
        _Float16*    dst = z == 0 ? d0 : z == 1 ? d1 : z == 2 ? d2 : z == 3 ? d3 : d4;
        const int r0 = (rem & 15) * 64, c0 = (rem >> 4) * 64;
        const int r = tid >> 4, c4 = (tid & 15) * 4;
        #pragma unroll
        for (int rr = 0; rr < 64; rr += 16) {
            float4 v = *(const float4*)(src + (size_t)(r0 + r + rr) * 1024 + c0 + c4);
            T[c4 + 0][r + rr] = (_Float16)v.x;
            T[c4 + 1][r + rr] = (_Float16)v.y;
            T[c4 + 2][r + rr] = (_Float16)v.z;
            T[c4 + 3][r + rr] = (_Float16)v.w;
        }
        __syncthreads();
        const int orow = tid >> 2, seg = (tid & 3) * 16;
        half8 h0 = *(const half8*)&T[orow][seg];
        half8 h1 = *(const half8*)&T[orow][seg + 8];
        *(half8*)(dst + (size_t)(c0 + orow) * 1024 + r0 + seg)     = h0;
        *(half8*)(dst + (size_t)(c0 + orow) * 1024 + r0 + seg + 8) = h1;
    } else {
        size_t i = ((size_t)(bx - 1280) * 256 + tid) * 8;
        if (i >= 8389632ull) return;
        const float* src; _Float16* dst; size_t off;
        if (i < 2097152ull)      { src = x;   dst = x16;   off = i; }
        else if (i < 6291456ull) { src = mem; dst = mem16; off = i - 2097152ull; }
        else                     { src = rel; dst = rel16; off = i - 6291456ull; }
        float4 a = *(const float4*)(src + off);
        float4 b = *(const float4*)(src + off + 4);
        half8 h;
        h[0]=(_Float16)a.x; h[1]=(_Float16)a.y; h[2]=(_Float16)a.z; h[3]=(_Float16)a.w;
        h[4]=(_Float16)b.x; h[5]=(_Float16)b.y; h[6]=(_Float16)b.z; h[7]=(_Float16)b.w;
        *(half8*)(dst + off) = h;
    }
}

// ---------------------------------------------------------------------------
// 128x128-tile projection GEMM (fp16, global_load_lds, XOR swizzle, BK=64).
// bx: [0,16) Q; [16,48) K; [48,80) V(transposed out); [80,97) R. grid.y=8.
// ---------------------------------------------------------------------------
__global__ __launch_bounds__(256) void proj3_kernel(
    const _Float16* __restrict__ x16, const _Float16* __restrict__ mem16,
    const _Float16* __restrict__ rel16,
    const _Float16* __restrict__ Wqt, const _Float16* __restrict__ Wkt,
    const _Float16* __restrict__ Wvt, const _Float16* __restrict__ Wrt,
    const float* __restrict__ ub, const float* __restrict__ vb,
    unsigned short* __restrict__ qu, _Float16* __restrict__ qv,
    unsigned short* __restrict__ kb, unsigned short* __restrict__ vtb,
    _Float16* __restrict__ rb)
{
    alignas(16) __shared__ _Float16 As[128 * 64];
    alignas(16) __shared__ _Float16 Bs[128 * 64];
    const int tid = threadIdx.x;
    const int lane = tid & 63, w = tid >> 6, c = lane & 15, g = lane >> 4;
    const int bx = blockIdx.x, col0 = blockIdx.y * 128;

    int mode, row0, rowmax;
    const _Float16 *Ap, *Bp;
    if (bx < 16)      { mode = 0; row0 = bx * 128;        rowmax = 2047; Ap = x16;   Bp = Wqt; }
    else if (bx < 48) { mode = 1; row0 = (bx - 16) * 128; rowmax = 4095; Ap = mem16; Bp = Wkt; }
    else if (bx < 80) { mode = 2; row0 = (bx - 48) * 128; rowmax = 4095; Ap = mem16; Bp = Wvt; }
    else              { mode = 3; row0 = (bx - 80) * 128; rowmax = 2048; Ap = rel16; Bp = Wrt; }

    const int qr = (w & 1) * 64, qc = (w >> 1) * 64;
    const int srow = lane >> 3, phys = lane & 7;
    f32x4 acc[4][4] = {};

    for (int k0 = 0; k0 < 1024; k0 += 64) {
        #pragma unroll
        for (int q = 0; q < 4; q++) {
            int row = 32 * w + 8 * q + srow;
            int log = phys ^ (row & 7);
            int ar = row0 + row; if (ar > rowmax) ar = rowmax;
            lds_dma16(Ap + (size_t)ar * 1024 + k0 + log * 8, &As[(32 * w + 8 * q) * 64]);
            lds_dma16(Bp + (size_t)(col0 + row) * 1024 + k0 + log * 8, &Bs[(32 * w + 8 * q) * 64]);
        }
        __syncthreads();
        #pragma unroll
        for (int s = 0; s < 2; s++) {
            half8 af[4], bf[4];
            #pragma unroll
            for (int i = 0; i < 4; i++) {
                int row = qr + 16 * i + c;
                af[i] = *(const half8*)&As[row * 64 + ((4 * s + g) ^ (row & 7)) * 8];
            }
            #pragma unroll
            for (int j = 0; j < 4; j++) {
                int row = qc + 16 * j + c;
                bf[j] = *(const half8*)&Bs[row * 64 + ((4 * s + g) ^ (row & 7)) * 8];
            }
            #pragma unroll
            for (int i = 0; i < 4; i++)
                #pragma unroll
                for (int j = 0; j < 4; j++)
                    acc[i][j] = __builtin_amdgcn_mfma_f32_16x16x32_f16(af[i], bf[j], acc[i][j], 0, 0, 0);
        }
        __syncthreads();
    }

    #pragma unroll
    for (int i = 0; i < 4; i++) {
        #pragma unroll
        for (int j = 0; j < 4; j++) {
            const int cg = col0 + qc + 16 * j + c;
            const int rbase = row0 + qr + 16 * i + 4 * g;
            if (mode == 0) {
                float u = ub[cg], v = vb[cg];
                #pragma unroll
                for (int rg = 0; rg < 4; rg++) {
                    size_t o = (size_t)(rbase + rg) * 1024 + cg;
                    qu[o] = bf16_rne(acc[i][j][rg] + u);
                    qv[o] = (_Float16)((acc[i][j][rg] + v) * C_SCALE);
                }
            } else if (mode == 1) {
                #pragma unroll
                for (int rg = 0; rg < 4; rg++)
                    kb[(size_t)(rbase + rg) * 1024 + cg] = bf16_rne(acc[i][j][rg]);
            } else if (mode == 2) {
                us4 pk;
                #pragma unroll
                for (int rg = 0; rg < 4; rg++) pk[rg] = bf16_rne(acc[i][j][rg]);
                int b = rbase >> 11, s = rbase & 2047;
                *(us4*)&vtb[((size_t)(b * 16 + (cg >> 6)) * 64 + (cg & 63)) * 2048 + s] = pk;
            } else {
                #pragma unroll
                for (int rg = 0; rg < 4; rg++) {
                    int r_g = rbase + rg;
                    if (r_g < 2049)
                        rb[((size_t)(cg >> 6) * 2049 + r_g) * 64 + (cg & 63)] = (_Float16)acc[i][j][rg];
                }
            }
        }
    }
}

// ---------------------------------------------------------------------------
// Barrier-free flash attention. Ps and BDT are wave-private (rows/cols
// [16w,16w+16)), so no __syncthreads anywhere. K/V B-fragments are loaded
// directly from global (L2-resident via XCD-aware block decode: all 16
// t-blocks of one (bn,part) land on one XCD). BD bias computed on the fly
// into a 128-col circular wave-private window; BD(k+1) sits between
// softmax(k) and PV(k) so its MFMAs overlap softmax VALU on the other pipe.
// LDS = 26.9 KB -> ~6 blocks/CU.
// ---------------------------------------------------------------------------
__global__ __launch_bounds__(256, 4) void flash_kernel(
    const unsigned short* __restrict__ qu, const _Float16* __restrict__ qv,
    const unsigned short* __restrict__ kg, const unsigned short* __restrict__ vt,
    const _Float16* __restrict__ rb, _Float16* __restrict__ po, float* __restrict__ pl)
{
    __shared__ unsigned short Ps[64 * 70];
    __shared__ _Float16 BDT[128 * 70];
    const int tid = threadIdx.x;
    const int lane = tid & 63, w = tid >> 6, c = lane & 15, g = lane >> 4;
    const int id = blockIdx.x;
    const int p_pair = id & 127;
    const int t0 = (id >> 7) * 64;
    const int bn = p_pair >> 2, part = p_pair & 3;
    const int b = bn >> 4, n = bn & 15;
    const int s_start = part * 512;

    // Q fragments
    const unsigned short* qp = qu + (size_t)(b * 1024 + t0 + 16 * w + c) * 1024 + n * 64 + g * 8;
    bf16x8 qf0 = *(const bf16x8*)qp;
    bf16x8 qf1 = *(const bf16x8*)(qp + 32);
    const _Float16* qvp = qv + (size_t)(b * 1024 + t0 + 16 * w + c) * 1024 + n * 64 + g * 8;
    half8 av0 = *(const half8*)qvp;
    half8 av1 = *(const half8*)(qvp + 32);
    int r2 = t0 + 16 * w + c + 1; if (r2 > 1023) r2 = 1023;   // row t=1023 never uses wrap
    const _Float16* qvp2 = qv + (size_t)(b * 1024 + r2) * 1024 + n * 64 + g * 8;
    half8 aw0 = *(const half8*)qvp2;
    half8 aw1 = *(const half8*)(qvp2 + 32);

    const _Float16* rbase = rb + (size_t)n * 2049 * 64;
    // per-lane K/V B-fragment base pointers (row = 16j+c, cols 8g.. / 32+8g..)
    const unsigned short* kR = kg + (size_t)(b * 2048 + s_start + c) * 1024 + n * 64 + g * 8;
    const unsigned short* vR = vt + ((size_t)bn * 64 + c) * 2048 + s_start + g * 8;

    f32x4 o[4] = {};
    float l_i[4] = {0.f, 0.f, 0.f, 0.f};

    auto bd_one = [&](int Dbase, int j) {
        int Dl = Dbase + 16 * j + c;
        int Dmin = Dbase + 16 * j;
        int mm = (Dl <= 1026) ? (Dl + 1023 > 2048 ? 2048 : Dl + 1023) : Dl - 1027;
        const _Float16* rp = rbase + (size_t)mm * 64 + g * 8;
        half8 r0 = *(const half8*)rp;
        half8 r1 = *(const half8*)(rp + 32);
        f32x4 z;
        if (Dmin + 15 <= 1026) {
            f32x4 zm = {};
            zm = __builtin_amdgcn_mfma_f32_16x16x32_f16(av0, r0, zm, 0, 0, 0);
            zm = __builtin_amdgcn_mfma_f32_16x16x32_f16(av1, r1, zm, 0, 0, 0);
            z = zm;
        } else if (Dmin >= 1027) {
            f32x4 zw = {};
            zw = __builtin_amdgcn_mfma_f32_16x16x32_f16(aw0, r0, zw, 0, 0, 0);
            zw = __builtin_amdgcn_mfma_f32_16x16x32_f16(aw1, r1, zw, 0, 0, 0);
            z = zw;
        } else {
            f32x4 zm = {}, zw = {};
            zm = __builtin_amdgcn_mfma_f32_16x16x32_f16(av0, r0, zm, 0, 0, 0);
            zm = __builtin_amdgcn_mfma_f32_16x16x32_f16(av1, r1, zm, 0, 0, 0);
            zw = __builtin_amdgcn_mfma_f32_16x16x32_f16(aw0, r0, zw, 0, 0, 0);
            zw = __builtin_amdgcn_mfma_f32_16x16x32_f16(aw1, r1, zw, 0, 0, 0);
            z = (Dl >= 1027) ? zw : zm;
        }
        if (Dl == 1026) { z[0] = 0.f; z[1] = 0.f; z[2] = 0.f; z[3] = 0.f; }
        half4 hv;
        #pragma unroll
        for (int rg = 0; rg < 4; rg++) hv[rg] = (_Float16)z[rg];
        *(half4*)&BDT[(Dl & 127) * 70 + 16 * w + 4 * g] = hv;  // wave-private cols
    };

    const int d0 = s_start - t0;
    // prologue: full 128-col BD window for tile 0
    #pragma unroll
    for (int j = 0; j < 8; j++) bd_one(d0 - 63, j);

    for (int kk = 0; kk < 8; kk++) {
        const int diff0 = d0 + kk * 64;

        // ---- QK (direct-global K fragments) + unnormalized softmax ----
        #pragma unroll
        for (int j = 0; j < 4; j++) {
            const unsigned short* kp = kR + (size_t)(kk * 64 + 16 * j) * 1024;
            bf16x8 kf0 = *(const bf16x8*)kp;
            bf16x8 kf1 = *(const bf16x8*)(kp + 32);
            f32x4 sa = {};
            sa = __builtin_amdgcn_mfma_f32_16x16x32_bf16(qf0, kf0, sa, 0, 0, 0);
            sa = __builtin_amdgcn_mfma_f32_16x16x32_bf16(qf1, kf1, sa, 0, 0, 0);
            #pragma unroll
            for (int rg = 0; rg < 4; rg++) {
                int tt = 16 * w + 4 * g + rg;
                int D = diff0 + 16 * j + c - tt;
                float bdt = (float)BDT[(D & 127) * 70 + tt];
                float p = exp2f(fmaf(sa[rg], C_SCALE, bdt));
                l_i[rg] += p;
                Ps[tt * 70 + 16 * j + c] = bf16_rne(p);     // wave-private rows
            }
        }

        // ---- BD(k+1): overlaps softmax VALU via MFMA pipe; window slots it
        // overwrites were only read by THIS wave above (in-order LDS) ----
        if (kk < 7) {
            #pragma unroll
            for (int j = 0; j < 4; j++) bd_one(diff0 + 65, j);
        }

        // ---- PV (direct-global V fragments) ----
        bf16x8 pf0 = *(const bf16x8*)&Ps[(16 * w + c) * 70 + g * 8];
        bf16x8 pf1 = *(const bf16x8*)&Ps[(16 * w + c) * 70 + 32 + g * 8];
        #pragma unroll
        for (int j = 0; j < 4; j++) {
            const unsigned short* vp = vR + (size_t)(16 * j) * 2048 + kk * 64;
            bf16x8 vf0 = *(const bf16x8*)vp;
            bf16x8 vf1 = *(const bf16x8*)(vp + 32);
            o[j] = __builtin_amdgcn_mfma_f32_16x16x32_bf16(pf0, vf0, o[j], 0, 0, 0);
            o[j] = __builtin_amdgcn_mfma_f32_16x16x32_bf16(pf1, vf1, o[j], 0, 0, 0);
        }
    }

    #pragma unroll
    for (int rg = 0; rg < 4; rg++) {
        float s2 = l_i[rg];
        #pragma unroll
        for (int off = 1; off < 16; off <<= 1)
            s2 += __shfl_xor(s2, off, 16);
        int t = t0 + 16 * w + 4 * g + rg;
        size_t rowb = ((size_t)part * 32 + bn) * 1024 + t;
        if (c == 0) pl[rowb] = s2;
        float inv = 1.f / s2;
        #pragma unroll
        for (int j = 0; j < 4; j++)
            po[rowb * 64 + 16 * j + c] = (_Float16)(o[j][rg] * inv);
    }
}

// ---------------------------------------------------------------------------
// Combine: attn = sum_p l_p * po_p / sum_p l_p
// ---------------------------------------------------------------------------
__global__ __launch_bounds__(256) void combine_kernel(
    const _Float16* __restrict__ po, const float* __restrict__ pl,
    _Float16* __restrict__ attn)
{
    int f = blockIdx.x * 256 + threadIdx.x;
    int h = f & 63, t = (f >> 6) & 1023, bn = f >> 16;
    float os = 0.f, ls = 0.f;
    #pragma unroll
    for (int p = 0; p < 4; p++) {
        size_t rowb = ((size_t)p * 32 + bn) * 1024 + t;
        float lp = pl[rowb];
        os += lp * (float)po[rowb * 64 + h];
        ls += lp;
    }
    int b = bn >> 4, n = bn & 15;
    attn[((size_t)b * 1024 + t) * 1024 + n * 64 + h] = (_Float16)(os / ls);
}

// ---------------------------------------------------------------------------
// Output GEMM, 128x128 tile: out[bt,f] = sum_nh attn[bt,nh]*Woutt[f,nh] + b_out[f]
// ---------------------------------------------------------------------------
__global__ __launch_bounds__(256) void out3_kernel(
    const _Float16* __restrict__ A, const _Float16* __restrict__ Bt,
    const float* __restrict__ bias, float* __restrict__ out)
{
    alignas(16) __shared__ _Float16 As[128 * 64];
    alignas(16) __shared__ _Float16 Bs[128 * 64];
    const int tid = threadIdx.x;
    const int lane = tid & 63, w = tid >> 6, c = lane & 15, g = lane >> 4;
    const int row0 = blockIdx.x * 128, col0 = blockIdx.y * 128;
    const int qr = (w & 1) * 64, qc = (w >> 1) * 64;
    const int srow = lane >> 3, phys = lane & 7;
    f32x4 acc[4][4] = {};

    for (int k0 = 0; k0 < 1024; k0 += 64) {
        #pragma unroll
        for (int q = 0; q < 4; q++) {
            int row = 32 * w + 8 * q + srow;
            int log = phys ^ (row & 7);
            lds_dma16(A  + (size_t)(row0 + row) * 1024 + k0 + log * 8, &As[(32 * w + 8 * q) * 64]);
            lds_dma16(Bt + (size_t)(col0 + row) * 1024 + k0 + log * 8, &Bs[(32 * w + 8 * q) * 64]);
        }
        __syncthreads();
        #pragma unroll
        for (int s = 0; s < 2; s++) {
            half8 af[4], bf[4];
            #pragma unroll
            for (int i = 0; i < 4; i++) {
                int row = qr + 16 * i + c;
                af[i] = *(const half8*)&As[row * 64 + ((4 * s + g) ^ (row & 7)) * 8];
            }
            #pragma unroll
            for (int j = 0; j < 4; j++) {
                int row = qc + 16 * j + c;
                bf[j] = *(const half8*)&Bs[row * 64 + ((4 * s + g) ^ (row & 7)) * 8];
            }
            #pragma unroll
            for (int i = 0; i < 4; i++)
                #pragma unroll
                for (int j = 0; j < 4; j++)
                    acc[i][j] = __builtin_amdgcn_mfma_f32_16x16x32_f16(af[i], bf[j], acc[i][j], 0, 0, 0);
        }
        __syncthreads();
    }
    #pragma unroll
    for (int i = 0; i < 4; i++)
        #pragma unroll
        for (int j = 0; j < 4; j++) {
            const int cg = col0 + qc + 16 * j + c;
            const int rbase = row0 + qr + 16 * i + 4 * g;
            #pragma unroll
            for (int rg = 0; rg < 4; rg++)
                out[(size_t)(rbase + rg) * 1024 + cg] = acc[i][j][rg] + bias[cg];
        }
}

extern "C" void kernel_launch(void* const* d_in, const int* in_sizes, int n_in,
                              void* d_out, int out_size, void* d_ws, size_t ws_size,
                              hipStream_t stream)
{
    const float* x    = (const float*)d_in[0];
    const float* rel  = (const float*)d_in[1];
    const float* mem  = (const float*)d_in[2];
    const float* Wq   = (const float*)d_in[3];
    const float* Wk   = (const float*)d_in[4];
    const float* Wv   = (const float*)d_in[5];
    const float* Wr   = (const float*)d_in[6];
    const float* ub   = (const float*)d_in[7];
    const float* vb   = (const float*)d_in[8];
    const float* Wout = (const float*)d_in[9];
    const float* bout = (const float*)d_in[10];
    float* out = (float*)d_out;

    char* ws = (char*)d_ws;
    unsigned short* qu    = (unsigned short*)(ws);                   // 4 MB   bf16 [B,T,NH]
    _Float16*       qv    = (_Float16*)(ws + (4ull << 20));          // 4 MB   fp16 [B,T,NH] (*C_SCALE)
    unsigned short* kb    = (unsigned short*)(ws + (8ull << 20));    // 8 MB   bf16 [B,S,NH]
    unsigned short* vtb   = (unsigned short*)(ws + (16ull << 20));   // 8 MB   bf16 [B,N,H,S]
    _Float16*       rb    = (_Float16*)(ws + (24ull << 20));         // 4.2 MB fp16 [N,M,H]
    _Float16*       attn  = (_Float16*)(ws + (29ull << 20));         // 4 MB   fp16 [B,T,NH]
    _Float16*       po    = (_Float16*)(ws + (33ull << 20));         // 16.8MB fp16 [4,BN,T,H]
    float*          pl    = (float*)(ws + (50ull << 20));            // 0.5 MB fp32 [4,BN,T]
    _Float16*       x16   = (_Float16*)(ws + (51ull << 20));         // 4 MB
    _Float16*       mem16 = (_Float16*)(ws + (55ull << 20));         // 8 MB
    _Float16*       rel16 = (_Float16*)(ws + (63ull << 20));         // 4.2 MB
    _Float16*       Wqt   = (_Float16*)(ws + (68ull << 20));         // 2 MB each
    _Float16*       Wkt   = (_Float16*)(ws + (70ull << 20));
    _Float16*       Wvt   = (_Float16*)(ws + (72ull << 20));
    _Float16*       Wrt   = (_Float16*)(ws + (74ull << 20));
    _Float16*       Woutt = (_Float16*)(ws + (76ull << 20));

    prep_kernel<<<dim3(5377), 256, 0, stream>>>(
        x, mem, rel, Wq, Wk, Wv, Wr, Wout,
        x16, mem16, rel16, Wqt, Wkt, Wvt, Wrt, Woutt);
    proj3_kernel<<<dim3(97, 8), 256, 0, stream>>>(
        x16, mem16, rel16, Wqt, Wkt, Wvt, Wrt, ub, vb, qu, qv, kb, vtb, rb);
    flash_kernel<<<dim3(2048), 256, 0, stream>>>(qu, qv, kb, vtb, rb, po, pl);
    combine_kernel<<<dim3(8192), 256, 0, stream>>>(po, pl, attn);
    out3_kernel<<<dim3(16, 8), 256, 0, stream>>>(attn, Woutt, bout, out);
}

// Round 7
// 308.346 us; speedup vs baseline: 1.1861x; 1.1861x over previous
//
#include <hip/hip_runtime.h>
#include <cmath>

#define C_SCALE 0.18033688011112042f   // 0.125 * log2(e)

typedef __attribute__((ext_vector_type(8))) short bf16x8;
typedef __attribute__((ext_vector_type(8))) _Float16 half8;
typedef __attribute__((ext_vector_type(4))) _Float16 half4;
typedef __attribute__((ext_vector_type(4))) float f32x4;
typedef __attribute__((ext_vector_type(4))) unsigned short us4;

__device__ inline unsigned short bf16_rne(float f) {
    unsigned u = __builtin_bit_cast(unsigned, f);
    u += 0x7fff + ((u >> 16) & 1);
    return (unsigned short)(u >> 16);
}

__device__ inline void lds_dma16(const _Float16* g, _Float16* l) {
    __builtin_amdgcn_global_load_lds(
        (__attribute__((address_space(1))) void*)(void*)g,
        (__attribute__((address_space(3))) void*)(void*)l, 16, 0, 0);
}

// ---------------------------------------------------------------------------
// Fused prep: bx<1280 -> transpose W matrices fp32->fp16 (Wt[col][k]);
// bx>=1280 -> fp32->fp16 convert of x/mem/rel.
// ---------------------------------------------------------------------------
__global__ __launch_bounds__(256) void prep_kernel(
    const float* __restrict__ x, const float* __restrict__ mem,
    const float* __restrict__ rel,
    const float* __restrict__ s0, const float* __restrict__ s1,
    const float* __restrict__ s2, const float* __restrict__ s3,
    const float* __restrict__ s4,
    _Float16* __restrict__ x16, _Float16* __restrict__ mem16,
    _Float16* __restrict__ rel16,
    _Float16* __restrict__ d0, _Float16* __restrict__ d1,
    _Float16* __restrict__ d2, _Float16* __restrict__ d3,
    _Float16* __restrict__ d4)
{
    const int bx = blockIdx.x, tid = threadIdx.x;
    if (bx < 1280) {
        __shared__ _Float16 T[64][72];
        const int z = bx >> 8, rem = bx & 255;
        const float* src = z == 0 ? s0 : z == 1 ? s1 : z == 2 ? s2 : z == 3 ? s3 : s4;
        _Float16*    dst = z == 0 ? d0 : z == 1 ? d1 : z == 2 ? d2 : z == 3 ? d3 : d4;
        const int r0 = (rem & 15) * 64, c0 = (rem >> 4) * 64;
        const int r = tid >> 4, c4 = (tid & 15) * 4;
        #pragma unroll
        for (int rr = 0; rr < 64; rr += 16) {
            float4 v = *(const float4*)(src + (size_t)(r0 + r + rr) * 1024 + c0 + c4);
            T[c4 + 0][r + rr] = (_Float16)v.x;
            T[c4 + 1][r + rr] = (_Float16)v.y;
            T[c4 + 2][r + rr] = (_Float16)v.z;
            T[c4 + 3][r + rr] = (_Float16)v.w;
        }
        __syncthreads();
        const int orow = tid >> 2, seg = (tid & 3) * 16;
        half8 h0 = *(const half8*)&T[orow][seg];
        half8 h1 = *(const half8*)&T[orow][seg + 8];
        *(half8*)(dst + (size_t)(c0 + orow) * 1024 + r0 + seg)     = h0;
        *(half8*)(dst + (size_t)(c0 + orow) * 1024 + r0 + seg + 8) = h1;
    } else {
        size_t i = ((size_t)(bx - 1280) * 256 + tid) * 8;
        if (i >= 8389632ull) return;
        const float* src; _Float16* dst; size_t off;
        if (i < 2097152ull)      { src = x;   dst = x16;   off = i; }
        else if (i < 6291456ull) { src = mem; dst = mem16; off = i - 2097152ull; }
        else                     { src = rel; dst = rel16; off = i - 6291456ull; }
        float4 a = *(const float4*)(src + off);
        float4 b = *(const float4*)(src + off + 4);
        half8 h;
        h[0]=(_Float16)a.x; h[1]=(_Float16)a.y; h[2]=(_Float16)a.z; h[3]=(_Float16)a.w;
        h[4]=(_Float16)b.x; h[5]=(_Float16)b.y; h[6]=(_Float16)b.z; h[7]=(_Float16)b.w;
        *(half8*)(dst + off) = h;
    }
}

// ---------------------------------------------------------------------------
// 128x128-tile projection GEMM (fp16, global_load_lds, XOR swizzle, BK=64).
// bx: [0,16) Q; [16,48) K; [48,80) V(transposed out); [80,97) R. grid.y=8.
// ---------------------------------------------------------------------------
__global__ __launch_bounds__(256) void proj3_kernel(
    const _Float16* __restrict__ x16, const _Float16* __restrict__ mem16,
    const _Float16* __restrict__ rel16,
    const _Float16* __restrict__ Wqt, const _Float16* __restrict__ Wkt,
    const _Float16* __restrict__ Wvt, const _Float16* __restrict__ Wrt,
    const float* __restrict__ ub, const float* __restrict__ vb,
    unsigned short* __restrict__ qu, _Float16* __restrict__ qv,
    unsigned short* __restrict__ kb, unsigned short* __restrict__ vtb,
    _Float16* __restrict__ rb)
{
    alignas(16) __shared__ _Float16 As[128 * 64];
    alignas(16) __shared__ _Float16 Bs[128 * 64];
    const int tid = threadIdx.x;
    const int lane = tid & 63, w = tid >> 6, c = lane & 15, g = lane >> 4;
    const int bx = blockIdx.x, col0 = blockIdx.y * 128;

    int mode, row0, rowmax;
    const _Float16 *Ap, *Bp;
    if (bx < 16)      { mode = 0; row0 = bx * 128;        rowmax = 2047; Ap = x16;   Bp = Wqt; }
    else if (bx < 48) { mode = 1; row0 = (bx - 16) * 128; rowmax = 4095; Ap = mem16; Bp = Wkt; }
    else if (bx < 80) { mode = 2; row0 = (bx - 48) * 128; rowmax = 4095; Ap = mem16; Bp = Wvt; }
    else              { mode = 3; row0 = (bx - 80) * 128; rowmax = 2048; Ap = rel16; Bp = Wrt; }

    const int qr = (w & 1) * 64, qc = (w >> 1) * 64;
    const int srow = lane >> 3, phys = lane & 7;
    f32x4 acc[4][4] = {};

    for (int k0 = 0; k0 < 1024; k0 += 64) {
        #pragma unroll
        for (int q = 0; q < 4; q++) {
            int row = 32 * w + 8 * q + srow;
            int log = phys ^ (row & 7);
            int ar = row0 + row; if (ar > rowmax) ar = rowmax;
            lds_dma16(Ap + (size_t)ar * 1024 + k0 + log * 8, &As[(32 * w + 8 * q) * 64]);
            lds_dma16(Bp + (size_t)(col0 + row) * 1024 + k0 + log * 8, &Bs[(32 * w + 8 * q) * 64]);
        }
        __syncthreads();
        #pragma unroll
        for (int s = 0; s < 2; s++) {
            half8 af[4], bf[4];
            #pragma unroll
            for (int i = 0; i < 4; i++) {
                int row = qr + 16 * i + c;
                af[i] = *(const half8*)&As[row * 64 + ((4 * s + g) ^ (row & 7)) * 8];
            }
            #pragma unroll
            for (int j = 0; j < 4; j++) {
                int row = qc + 16 * j + c;
                bf[j] = *(const half8*)&Bs[row * 64 + ((4 * s + g) ^ (row & 7)) * 8];
            }
            #pragma unroll
            for (int i = 0; i < 4; i++)
                #pragma unroll
                for (int j = 0; j < 4; j++)
                    acc[i][j] = __builtin_amdgcn_mfma_f32_16x16x32_f16(af[i], bf[j], acc[i][j], 0, 0, 0);
        }
        __syncthreads();
    }

    #pragma unroll
    for (int i = 0; i < 4; i++) {
        #pragma unroll
        for (int j = 0; j < 4; j++) {
            const int cg = col0 + qc + 16 * j + c;
            const int rbase = row0 + qr + 16 * i + 4 * g;
            if (mode == 0) {
                float u = ub[cg], v = vb[cg];
                #pragma unroll
                for (int rg = 0; rg < 4; rg++) {
                    size_t o = (size_t)(rbase + rg) * 1024 + cg;
                    qu[o] = bf16_rne(acc[i][j][rg] + u);
                    qv[o] = (_Float16)((acc[i][j][rg] + v) * C_SCALE);
                }
            } else if (mode == 1) {
                #pragma unroll
                for (int rg = 0; rg < 4; rg++)
                    kb[(size_t)(rbase + rg) * 1024 + cg] = bf16_rne(acc[i][j][rg]);
            } else if (mode == 2) {
                us4 pk;
                #pragma unroll
                for (int rg = 0; rg < 4; rg++) pk[rg] = bf16_rne(acc[i][j][rg]);
                int b = rbase >> 11, s = rbase & 2047;
                *(us4*)&vtb[((size_t)(b * 16 + (cg >> 6)) * 64 + (cg & 63)) * 2048 + s] = pk;
            } else {
                #pragma unroll
                for (int rg = 0; rg < 4; rg++) {
                    int r_g = rbase + rg;
                    if (r_g < 2049)
                        rb[((size_t)(cg >> 6) * 2049 + r_g) * 64 + (cg & 63)] = (_Float16)acc[i][j][rg];
                }
            }
        }
    }
}

// ---------------------------------------------------------------------------
// Flash attention, TRANSPOSED orientation: compute S^T = K·Q^T and
// O^T = V^T·P^T. Each wave owns 16 t-columns (t = t0+16w+c per lane).
//  - PsT[t][s]: b64 packed writes, b128 B-fragment reads (both vectorized)
//  - BDX[t][slot(D)]: BD computed transposed (A=r rows D, B=qv rows t) ->
//    half4 aligned writes AND half4 reads; slots 0..3 mirrored at 128..131
//    so 4-consecutive-D reads never wrap.
//  - K/V staged to LDS cooperatively (coalesced), 2 barriers/tile.
//  - l per lane is a single scalar; 2 shuffles at the end.
// XCD-aware decode: all 16 t-blocks of one (bn,part) on one XCD.
// ---------------------------------------------------------------------------
__global__ __launch_bounds__(256) void flash_kernel(
    const unsigned short* __restrict__ qu, const _Float16* __restrict__ qv,
    const unsigned short* __restrict__ kg, const unsigned short* __restrict__ vt,
    const _Float16* __restrict__ rb, _Float16* __restrict__ po, float* __restrict__ pl)
{
    __shared__ unsigned short Ks[64 * 70];   // [s][h]
    __shared__ unsigned short Vs[64 * 70];   // [h][s]
    __shared__ unsigned short PsT[64 * 70];  // [t][s]  (rows wave-private)
    __shared__ _Float16 BDX[64 * 138];       // [t][slot] (rows wave-private)
    const int tid = threadIdx.x;
    const int lane = tid & 63, w = tid >> 6, c = lane & 15, g = lane >> 4;
    const int id = blockIdx.x;
    const int p_pair = id & 127;
    const int t0 = (id >> 7) * 64;
    const int bn = p_pair >> 2, part = p_pair & 3;
    const int b = bn >> 4, n = bn & 15;
    const int s_start = part * 512;
    const int d0 = s_start - t0;

    // Q fragments as B-operands: row t = t0+16w+c, 8 cols at 8g / 32+8g
    const int tg = t0 + 16 * w + c;
    const unsigned short* qp = qu + (size_t)(b * 1024 + tg) * 1024 + n * 64 + g * 8;
    bf16x8 qf0 = *(const bf16x8*)qp;
    bf16x8 qf1 = *(const bf16x8*)(qp + 32);
    const _Float16* qvp = qv + (size_t)(b * 1024 + tg) * 1024 + n * 64 + g * 8;
    half8 av0 = *(const half8*)qvp;
    half8 av1 = *(const half8*)(qvp + 32);
    int tg2 = tg + 1; if (tg2 > 1023) tg2 = 1023;   // t=1023 never uses wrap
    const _Float16* qvp2 = qv + (size_t)(b * 1024 + tg2) * 1024 + n * 64 + g * 8;
    half8 aw0 = *(const half8*)qvp2;
    half8 aw1 = *(const half8*)(qvp2 + 32);

    const _Float16* rbase = rb + (size_t)n * 2049 * 64;

    f32x4 o[4] = {};
    float l_acc = 0.f;

    const int myrow = (16 * w + c);          // this lane's t row in PsT/BDX

    // BD quad: 64 D-values [Dbase, Dbase+63] via 4 m-tiles; A=r rows D, B=qv.
    auto bd_quad = [&](int Dbase) {
        #pragma unroll
        for (int i = 0; i < 4; i++) {
            const int Dmin = Dbase + 16 * i;
            const int Drow = Dmin + c;       // this lane's A-fragment row
            int mm = (Drow <= 1026) ? (Drow + 1023 > 2048 ? 2048 : Drow + 1023)
                                    : Drow - 1027;
            const _Float16* rp = rbase + (size_t)mm * 64 + g * 8;
            half8 r0 = *(const half8*)rp;
            half8 r1 = *(const half8*)(rp + 32);
            f32x4 z;
            if (Dmin + 15 <= 1026) {
                f32x4 zm = {};
                zm = __builtin_amdgcn_mfma_f32_16x16x32_f16(r0, av0, zm, 0, 0, 0);
                zm = __builtin_amdgcn_mfma_f32_16x16x32_f16(r1, av1, zm, 0, 0, 0);
                z = zm;
            } else if (Dmin >= 1027) {
                f32x4 zw = {};
                zw = __builtin_amdgcn_mfma_f32_16x16x32_f16(r0, aw0, zw, 0, 0, 0);
                zw = __builtin_amdgcn_mfma_f32_16x16x32_f16(r1, aw1, zw, 0, 0, 0);
                z = zw;
            } else {
                f32x4 zm = {}, zw = {};
                zm = __builtin_amdgcn_mfma_f32_16x16x32_f16(r0, av0, zm, 0, 0, 0);
                zm = __builtin_amdgcn_mfma_f32_16x16x32_f16(r1, av1, zm, 0, 0, 0);
                zw = __builtin_amdgcn_mfma_f32_16x16x32_f16(r0, aw0, zw, 0, 0, 0);
                zw = __builtin_amdgcn_mfma_f32_16x16x32_f16(r1, aw1, zw, 0, 0, 0);
                #pragma unroll
                for (int rg = 0; rg < 4; rg++)
                    z[rg] = (Dmin + 4 * g + rg >= 1027) ? zw[rg] : zm[rg];
            }
            int dz = 1026 - Dmin - 4 * g;                   // zero D==1026
            if (dz >= 0 && dz < 4) z[dz] = 0.f;
            half4 hv;
            #pragma unroll
            for (int rg = 0; rg < 4; rg++) hv[rg] = (_Float16)z[rg];
            int slot0 = (Dmin + 4 * g - d0 + 63) & 127;     // 4-aligned
            _Float16* wp = &BDX[myrow * 138 + slot0];
            *(half4*)wp = hv;
            if (slot0 < 4) *(half4*)(wp + 128) = hv;        // wrap mirror
        }
    };

    // prologue: full 128-slot window for tile 0
    bd_quad(d0 - 63);
    bd_quad(d0 + 1);

    const int sr = tid >> 2, scc = (tid & 3) * 16;
    const unsigned short* kst = kg + (size_t)(b * 2048 + s_start + sr) * 1024 + n * 64 + scc;
    const unsigned short* vst = vt + ((size_t)bn * 64 + sr) * 2048 + s_start + scc;

    for (int kk = 0; kk < 8; kk++) {
        const int diff0 = d0 + kk * 64;

        // ---- stage K [s][h] and V^T [h][s] tiles (coalesced) ----
        *(uint4*)&Ks[sr * 70 + scc]     = *(const uint4*)(kst + (size_t)(kk * 64) * 1024);
        *(uint4*)&Ks[sr * 70 + scc + 8] = *(const uint4*)(kst + (size_t)(kk * 64) * 1024 + 8);
        *(uint4*)&Vs[sr * 70 + scc]     = *(const uint4*)(vst + kk * 64);
        *(uint4*)&Vs[sr * 70 + scc + 8] = *(const uint4*)(vst + kk * 64 + 8);
        __syncthreads();

        // ---- S^T = K·Q^T + softmax (vectorized bias read, packed P write) ----
        #pragma unroll
        for (int i = 0; i < 4; i++) {
            bf16x8 kf0 = *(const bf16x8*)&Ks[(16 * i + c) * 70 + 8 * g];
            bf16x8 kf1 = *(const bf16x8*)&Ks[(16 * i + c) * 70 + 32 + 8 * g];
            f32x4 sa = {};
            sa = __builtin_amdgcn_mfma_f32_16x16x32_bf16(kf0, qf0, sa, 0, 0, 0);
            sa = __builtin_amdgcn_mfma_f32_16x16x32_bf16(kf1, qf1, sa, 0, 0, 0);
            int slotb = (64 * kk + 16 * i + 4 * g - myrow + 63) & 127;
            half4 bd4 = *(const half4*)&BDX[myrow * 138 + slotb];
            us4 pk;
            #pragma unroll
            for (int rg = 0; rg < 4; rg++) {
                float p = exp2f(fmaf(sa[rg], C_SCALE, (float)bd4[rg]));
                l_acc += p;
                pk[rg] = bf16_rne(p);
            }
            *(us4*)&PsT[myrow * 70 + 16 * i + 4 * g] = pk;  // wave-private row
        }

        // ---- BD for next tile (overlaps softmax tail / PV on MFMA pipe) ----
        if (kk < 7) bd_quad(diff0 + 65);

        // ---- O^T += V^T·P^T ----
        bf16x8 pf0 = *(const bf16x8*)&PsT[myrow * 70 + 8 * g];
        bf16x8 pf1 = *(const bf16x8*)&PsT[myrow * 70 + 32 + 8 * g];
        #pragma unroll
        for (int i2 = 0; i2 < 4; i2++) {
            bf16x8 vf0 = *(const bf16x8*)&Vs[(16 * i2 + c) * 70 + 8 * g];
            bf16x8 vf1 = *(const bf16x8*)&Vs[(16 * i2 + c) * 70 + 32 + 8 * g];
            o[i2] = __builtin_amdgcn_mfma_f32_16x16x32_bf16(vf0, pf0, o[i2], 0, 0, 0);
            o[i2] = __builtin_amdgcn_mfma_f32_16x16x32_bf16(vf1, pf1, o[i2], 0, 0, 0);
        }
        __syncthreads();
    }

    // ---- epilogue: row sum over g-groups, normalized vector store ----
    float s2 = l_acc;
    s2 += __shfl_xor(s2, 16);
    s2 += __shfl_xor(s2, 32);
    size_t rowb = ((size_t)part * 32 + bn) * 1024 + tg;
    if (g == 0) pl[rowb] = s2;
    float inv = 1.f / s2;
    #pragma unroll
    for (int i2 = 0; i2 < 4; i2++) {
        half4 hv;
        #pragma unroll
        for (int rg = 0; rg < 4; rg++) hv[rg] = (_Float16)(o[i2][rg] * inv);
        *(half4*)&po[rowb * 64 + 16 * i2 + 4 * g] = hv;
    }
}

// ---------------------------------------------------------------------------
// Combine: attn = sum_p l_p * po_p / sum_p l_p
// ---------------------------------------------------------------------------
__global__ __launch_bounds__(256) void combine_kernel(
    const _Float16* __restrict__ po, const float* __restrict__ pl,
    _Float16* __restrict__ attn)
{
    int f = blockIdx.x * 256 + threadIdx.x;
    int h = f & 63, t = (f >> 6) & 1023, bn = f >> 16;
    float os = 0.f, ls = 0.f;
    #pragma unroll
    for (int p = 0; p < 4; p++) {
        size_t rowb = ((size_t)p * 32 + bn) * 1024 + t;
        float lp = pl[rowb];
        os += lp * (float)po[rowb * 64 + h];
        ls += lp;
    }
    int b = bn >> 4, n = bn & 15;
    attn[((size_t)b * 1024 + t) * 1024 + n * 64 + h] = (_Float16)(os / ls);
}

// ---------------------------------------------------------------------------
// Output GEMM, 128x128 tile: out[bt,f] = sum_nh attn[bt,nh]*Woutt[f,nh] + b_out[f]
// ---------------------------------------------------------------------------
__global__ __launch_bounds__(256) void out3_kernel(
    const _Float16* __restrict__ A, const _Float16* __restrict__ Bt,
    const float* __restrict__ bias, float* __restrict__ out)
{
    alignas(16) __shared__ _Float16 As[128 * 64];
    alignas(16) __shared__ _Float16 Bs[128 * 64];
    const int tid = threadIdx.x;
    const int lane = tid & 63, w = tid >> 6, c = lane & 15, g = lane >> 4;
    const int row0 = blockIdx.x * 128, col0 = blockIdx.y * 128;
    const int qr = (w & 1) * 64, qc = (w >> 1) * 64;
    const int srow = lane >> 3, phys = lane & 7;
    f32x4 acc[4][4] = {};

    for (int k0 = 0; k0 < 1024; k0 += 64) {
        #pragma unroll
        for (int q = 0; q < 4; q++) {
            int row = 32 * w + 8 * q + srow;
            int log = phys ^ (row & 7);
            lds_dma16(A  + (size_t)(row0 + row) * 1024 + k0 + log * 8, &As[(32 * w + 8 * q) * 64]);
            lds_dma16(Bt + (size_t)(col0 + row) * 1024 + k0 + log * 8, &Bs[(32 * w + 8 * q) * 64]);
        }
        __syncthreads();
        #pragma unroll
        for (int s = 0; s < 2; s++) {
            half8 af[4], bf[4];
            #pragma unroll
            for (int i = 0; i < 4; i++) {
                int row = qr + 16 * i + c;
                af[i] = *(const half8*)&As[row * 64 + ((4 * s + g) ^ (row & 7)) * 8];
            }
            #pragma unroll
            for (int j = 0; j < 4; j++) {
                int row = qc + 16 * j + c;
                bf[j] = *(const half8*)&Bs[row * 64 + ((4 * s + g) ^ (row & 7)) * 8];
            }
            #pragma unroll
            for (int i = 0; i < 4; i++)
                #pragma unroll
                for (int j = 0; j < 4; j++)
                    acc[i][j] = __builtin_amdgcn_mfma_f32_16x16x32_f16(af[i], bf[j], acc[i][j], 0, 0, 0);
        }
        __syncthreads();
    }
    #pragma unroll
    for (int i = 0; i < 4; i++)
        #pragma unroll
        for (int j = 0; j < 4; j++) {
            const int cg = col0 + qc + 16 * j + c;
            const int rbase = row0 + qr + 16 * i + 4 * g;
            #pragma unroll
            for (int rg = 0; rg < 4; rg++)
                out[(size_t)(rbase + rg) * 1024 + cg] = acc[i][j][rg] + bias[cg];
        }
}

extern "C" void kernel_launch(void* const* d_in, const int* in_sizes, int n_in,
                              void* d_out, int out_size, void* d_ws, size_t ws_size,
                              hipStream_t stream)
{
    const float* x    = (const float*)d_in[0];
    const float* rel  = (const float*)d_in[1];
    const float* mem  = (const float*)d_in[2];
    const float* Wq   = (const float*)d_in[3];
    const float* Wk   = (const float*)d_in[4];
    const float* Wv   = (const float*)d_in[5];
    const float* Wr   = (const float*)d_in[6];
    const float* ub   = (const float*)d_in[7];
    const float* vb   = (const float*)d_in[8];
    const float* Wout = (const float*)d_in[9];
    const float* bout = (const float*)d_in[10];
    float* out = (float*)d_out;

    char* ws = (char*)d_ws;
    unsigned short* qu    = (unsigned short*)(ws);                   // 4 MB   bf16 [B,T,NH]
    _Float16*       qv    = (_Float16*)(ws + (4ull << 20));          // 4 MB   fp16 [B,T,NH] (*C_SCALE)
    unsigned short* kb    = (unsigned short*)(ws + (8ull << 20));    // 8 MB   bf16 [B,S,NH]
    unsigned short* vtb   = (unsigned short*)(ws + (16ull << 20));   // 8 MB   bf16 [B,N,H,S]
    _Float16*       rb    = (_Float16*)(ws + (24ull << 20));         // 4.2 MB fp16 [N,M,H]
    _Float16*       attn  = (_Float16*)(ws + (29ull << 20));         // 4 MB   fp16 [B,T,NH]
    _Float16*       po    = (_Float16*)(ws + (33ull << 20));         // 16.8MB fp16 [4,BN,T,H]
    float*          pl    = (float*)(ws + (50ull << 20));            // 0.5 MB fp32 [4,BN,T]
    _Float16*       x16   = (_Float16*)(ws + (51ull << 20));         // 4 MB
    _Float16*       mem16 = (_Float16*)(ws + (55ull << 20));         // 8 MB
    _Float16*       rel16 = (_Float16*)(ws + (63ull << 20));         // 4.2 MB
    _Float16*       Wqt   = (_Float16*)(ws + (68ull << 20));         // 2 MB each
    _Float16*       Wkt   = (_Float16*)(ws + (70ull << 20));
    _Float16*       Wvt   = (_Float16*)(ws + (72ull << 20));
    _Float16*       Wrt   = (_Float16*)(ws + (74ull << 20));
    _Float16*       Woutt = (_Float16*)(ws + (76ull << 20));

    prep_kernel<<<dim3(5377), 256, 0, stream>>>(
        x, mem, rel, Wq, Wk, Wv, Wr, Wout,
        x16, mem16, rel16, Wqt, Wkt, Wvt, Wrt, Woutt);
    proj3_kernel<<<dim3(97, 8), 256, 0, stream>>>(
        x16, mem16, rel16, Wqt, Wkt, Wvt, Wrt, ub, vb, qu, qv, kb, vtb, rb);
    flash_kernel<<<dim3(2048), 256, 0, stream>>>(qu, qv, kb, vtb, rb, po, pl);
    combine_kernel<<<dim3(8192), 256, 0, stream>>>(po, pl, attn);
    out3_kernel<<<dim3(16, 8), 256, 0, stream>>>(attn, Woutt, bout, out);
}

// Round 8
// 283.893 us; speedup vs baseline: 1.2882x; 1.0861x over previous
//
#include <hip/hip_runtime.h>
#include <cmath>

#define C_SCALE 0.18033688011112042f   // 0.125 * log2(e)

typedef __attribute__((ext_vector_type(8))) short bf16x8;
typedef __attribute__((ext_vector_type(4))) short bf16x4;
typedef __attribute__((ext_vector_type(8))) _Float16 half8;
typedef __attribute__((ext_vector_type(4))) _Float16 half4;
typedef __attribute__((ext_vector_type(4))) float f32x4;
typedef __attribute__((ext_vector_type(4))) unsigned short us4;

__device__ inline unsigned short bf16_rne(float f) {
    unsigned u = __builtin_bit_cast(unsigned, f);
    u += 0x7fff + ((u >> 16) & 1);
    return (unsigned short)(u >> 16);
}

__device__ inline void lds_dma16(const void* g, void* l) {
    __builtin_amdgcn_global_load_lds(
        (__attribute__((address_space(1))) void*)(void*)g,
        (__attribute__((address_space(3))) void*)(void*)l, 16, 0, 0);
}

// ---------------------------------------------------------------------------
// Fused prep: bx<1280 -> transpose W matrices fp32->fp16 (Wt[col][k]);
// bx>=1280 -> fp32->fp16 convert of x/mem/rel.
// ---------------------------------------------------------------------------
__global__ __launch_bounds__(256) void prep_kernel(
    const float* __restrict__ x, const float* __restrict__ mem,
    const float* __restrict__ rel,
    const float* __restrict__ s0, const float* __restrict__ s1,
    const float* __restrict__ s2, const float* __restrict__ s3,
    const float* __restrict__ s4,
    _Float16* __restrict__ x16, _Float16* __restrict__ mem16,
    _Float16* __restrict__ rel16,
    _Float16* __restrict__ d0, _Float16* __restrict__ d1,
    _Float16* __restrict__ d2, _Float16* __restrict__ d3,
    _Float16* __restrict__ d4)
{
    const int bx = blockIdx.x, tid = threadIdx.x;
    if (bx < 1280) {
        __shared__ _Float16 T[64][72];
        const int z = bx >> 8, rem = bx & 255;
        const float* src = z == 0 ? s0 : z == 1 ? s1 : z == 2 ? s2 : z == 3 ? s3 : s4;
        _Float16*    dst = z == 0 ? d0 : z == 1 ? d1 : z == 2 ? d2 : z == 3 ? d3 : d4;
        const int r0 = (rem & 15) * 64, c0 = (rem >> 4) * 64;
        const int r = tid >> 4, c4 = (tid & 15) * 4;
        #pragma unroll
        for (int rr = 0; rr < 64; rr += 16) {
            float4 v = *(const float4*)(src + (size_t)(r0 + r + rr) * 1024 + c0 + c4);
            T[c4 + 0][r + rr] = (_Float16)v.x;
            T[c4 + 1][r + rr] = (_Float16)v.y;
            T[c4 + 2][r + rr] = (_Float16)v.z;
            T[c4 + 3][r + rr] = (_Float16)v.w;
        }
        __syncthreads();
        const int orow = tid >> 2, seg = (tid & 3) * 16;
        half8 h0 = *(const half8*)&T[orow][seg];
        half8 h1 = *(const half8*)&T[orow][seg + 8];
        *(half8*)(dst + (size_t)(c0 + orow) * 1024 + r0 + seg)     = h0;
        *(half8*)(dst + (size_t)(c0 + orow) * 1024 + r0 + seg + 8) = h1;
    } else {
        size_t i = ((size_t)(bx - 1280) * 256 + tid) * 8;
        if (i >= 8389632ull) return;
        const float* src; _Float16* dst; size_t off;
        if (i < 2097152ull)      { src = x;   dst = x16;   off = i; }
        else if (i < 6291456ull) { src = mem; dst = mem16; off = i - 2097152ull; }
        else                     { src = rel; dst = rel16; off = i - 6291456ull; }
        float4 a = *(const float4*)(src + off);
        float4 b = *(const float4*)(src + off + 4);
        half8 h;
        h[0]=(_Float16)a.x; h[1]=(_Float16)a.y; h[2]=(_Float16)a.z; h[3]=(_Float16)a.w;
        h[4]=(_Float16)b.x; h[5]=(_Float16)b.y; h[6]=(_Float16)b.z; h[7]=(_Float16)b.w;
        *(half8*)(dst + off) = h;
    }
}

// ---------------------------------------------------------------------------
// 128x128-tile projection GEMM (fp16, global_load_lds, XOR swizzle, BK=64).
// bx: [0,16) Q; [16,48) K; [48,80) V(transposed out); [80,97) R. grid.y=8.
// ---------------------------------------------------------------------------
__global__ __launch_bounds__(256) void proj3_kernel(
    const _Float16* __restrict__ x16, const _Float16* __restrict__ mem16,
    const _Float16* __restrict__ rel16,
    const _Float16* __restrict__ Wqt, const _Float16* __restrict__ Wkt,
    const _Float16* __restrict__ Wvt, const _Float16* __restrict__ Wrt,
    const float* __restrict__ ub, const float* __restrict__ vb,
    unsigned short* __restrict__ qu, _Float16* __restrict__ qv,
    unsigned short* __restrict__ kb, unsigned short* __restrict__ vtb,
    _Float16* __restrict__ rb)
{
    alignas(16) __shared__ _Float16 As[128 * 64];
    alignas(16) __shared__ _Float16 Bs[128 * 64];
    const int tid = threadIdx.x;
    const int lane = tid & 63, w = tid >> 6, c = lane & 15, g = lane >> 4;
    const int bx = blockIdx.x, col0 = blockIdx.y * 128;

    int mode, row0, rowmax;
    const _Float16 *Ap, *Bp;
    if (bx < 16)      { mode = 0; row0 = bx * 128;        rowmax = 2047; Ap = x16;   Bp = Wqt; }
    else if (bx < 48) { mode = 1; row0 = (bx - 16) * 128; rowmax = 4095; Ap = mem16; Bp = Wkt; }
    else if (bx < 80) { mode = 2; row0 = (bx - 48) * 128; rowmax = 4095; Ap = mem16; Bp = Wvt; }
    else              { mode = 3; row0 = (bx - 80) * 128; rowmax = 2048; Ap = rel16; Bp = Wrt; }

    const int qr = (w & 1) * 64, qc = (w >> 1) * 64;
    const int srow = lane >> 3, phys = lane & 7;
    f32x4 acc[4][4] = {};

    for (int k0 = 0; k0 < 1024; k0 += 64) {
        #pragma unroll
        for (int q = 0; q < 4; q++) {
            int row = 32 * w + 8 * q + srow;
            int log = phys ^ (row & 7);
            int ar = row0 + row; if (ar > rowmax) ar = rowmax;
            lds_dma16(Ap + (size_t)ar * 1024 + k0 + log * 8, &As[(32 * w + 8 * q) * 64]);
            lds_dma16(Bp + (size_t)(col0 + row) * 1024 + k0 + log * 8, &Bs[(32 * w + 8 * q) * 64]);
        }
        __syncthreads();
        #pragma unroll
        for (int s = 0; s < 2; s++) {
            half8 af[4], bf[4];
            #pragma unroll
            for (int i = 0; i < 4; i++) {
                int row = qr + 16 * i + c;
                af[i] = *(const half8*)&As[row * 64 + ((4 * s + g) ^ (row & 7)) * 8];
            }
            #pragma unroll
            for (int j = 0; j < 4; j++) {
                int row = qc + 16 * j + c;
                bf[j] = *(const half8*)&Bs[row * 64 + ((4 * s + g) ^ (row & 7)) * 8];
            }
            #pragma unroll
            for (int i = 0; i < 4; i++)
                #pragma unroll
                for (int j = 0; j < 4; j++)
                    acc[i][j] = __builtin_amdgcn_mfma_f32_16x16x32_f16(af[i], bf[j], acc[i][j], 0, 0, 0);
        }
        __syncthreads();
    }

    #pragma unroll
    for (int i = 0; i < 4; i++) {
        #pragma unroll
        for (int j = 0; j < 4; j++) {
            const int cg = col0 + qc + 16 * j + c;
            const int rbase = row0 + qr + 16 * i + 4 * g;
            if (mode == 0) {
                float u = ub[cg], v = vb[cg];
                #pragma unroll
                for (int rg = 0; rg < 4; rg++) {
                    size_t o = (size_t)(rbase + rg) * 1024 + cg;
                    qu[o] = bf16_rne(acc[i][j][rg] + u);
                    qv[o] = (_Float16)((acc[i][j][rg] + v) * C_SCALE);
                }
            } else if (mode == 1) {
                #pragma unroll
                for (int rg = 0; rg < 4; rg++)
                    kb[(size_t)(rbase + rg) * 1024 + cg] = bf16_rne(acc[i][j][rg]);
            } else if (mode == 2) {
                us4 pk;
                #pragma unroll
                for (int rg = 0; rg < 4; rg++) pk[rg] = bf16_rne(acc[i][j][rg]);
                int b = rbase >> 11, s = rbase & 2047;
                *(us4*)&vtb[((size_t)(b * 16 + (cg >> 6)) * 64 + (cg & 63)) * 2048 + s] = pk;
            } else {
                #pragma unroll
                for (int rg = 0; rg < 4; rg++) {
                    int r_g = rbase + rg;
                    if (r_g < 2049)
                        rb[((size_t)(cg >> 6) * 2049 + r_g) * 64 + (cg & 63)] = (_Float16)acc[i][j][rg];
                }
            }
        }
    }
}

// ---------------------------------------------------------------------------
// Flash attention v3 (S^T orientation):
//  - K/V/r staged via global_load_lds DMA into XOR-swizzled stride-64 LDS
//    (16B-aligned b128 reads; r-window staged once per block = 4x dedup and
//    coalesced vs the old per-wave 16-row gather).
//  - PV via mfma_f32_16x16x16bf16_1k: B-operand (P^T) fed DIRECTLY from the
//    softmax output registers (QK C-layout == PV-k16 B-layout). No Ps LDS.
//  - BDX bias window wave-private, circular 128 slots (+4 mirror).
// ---------------------------------------------------------------------------
__global__ __launch_bounds__(256) void flash_kernel(
    const unsigned short* __restrict__ qu, const _Float16* __restrict__ qv,
    const unsigned short* __restrict__ kg, const unsigned short* __restrict__ vt,
    const _Float16* __restrict__ rb, _Float16* __restrict__ po, float* __restrict__ pl)
{
    alignas(16) __shared__ unsigned short Ks[64 * 64];  // [s][h] swizzled
    alignas(16) __shared__ unsigned short Vs[64 * 64];  // [h][s] swizzled
    alignas(16) __shared__ _Float16 Rs[64 * 64];        // [D-local][h] swizzled
    alignas(16) __shared__ _Float16 BDX[64 * 132];      // [t][slot]
    const int tid = threadIdx.x;
    const int lane = tid & 63, w = tid >> 6, c = lane & 15, g = lane >> 4;
    const int id = blockIdx.x;
    const int p_pair = id & 127;
    const int t0 = (id >> 7) * 64;
    const int bn = p_pair >> 2, part = p_pair & 3;
    const int b = bn >> 4, n = bn & 15;
    const int s_start = part * 512;
    const int d0 = s_start - t0;
    const int cx = c & 7;

    // Q fragments (B-operands for S^T = K·Q^T): row t = t0+16w+c
    const int tg = t0 + 16 * w + c;
    const unsigned short* qp = qu + (size_t)(b * 1024 + tg) * 1024 + n * 64 + g * 8;
    bf16x8 qf0 = *(const bf16x8*)qp;
    bf16x8 qf1 = *(const bf16x8*)(qp + 32);
    const _Float16* qvp = qv + (size_t)(b * 1024 + tg) * 1024 + n * 64 + g * 8;
    half8 av0 = *(const half8*)qvp;
    half8 av1 = *(const half8*)(qvp + 32);
    int tg2 = tg + 1; if (tg2 > 1023) tg2 = 1023;   // t=1023 never uses wrap
    const _Float16* qvp2 = qv + (size_t)(b * 1024 + tg2) * 1024 + n * 64 + g * 8;
    half8 aw0 = *(const half8*)qvp2;
    half8 aw1 = *(const half8*)(qvp2 + 32);

    f32x4 o[4] = {};
    float l_acc = 0.f;
    const int myrow = 16 * w + c;

    // ---- DMA staging: per wave, 2 issues x 8 rows x (8 lanes x 16B) ----
    const int srow8 = lane >> 3;                 // row within 8-row group
    const int slog  = (lane & 7) ^ srow8;        // logical chunk (row&7==srow8)

    auto stage_k = [&](int kk) {
        #pragma unroll
        for (int iss = 0; iss < 2; iss++) {
            int row = 16 * w + 8 * iss + srow8;
            lds_dma16(kg + (size_t)(b * 2048 + s_start + kk * 64 + row) * 1024 + n * 64 + slog * 8,
                      &Ks[(16 * w + 8 * iss) * 64]);
        }
    };
    auto stage_v = [&](int kk) {
        #pragma unroll
        for (int iss = 0; iss < 2; iss++) {
            int row = 16 * w + 8 * iss + srow8;
            lds_dma16(vt + ((size_t)bn * 64 + row) * 2048 + s_start + kk * 64 + slog * 8,
                      &Vs[(16 * w + 8 * iss) * 64]);
        }
    };
    auto stage_r = [&](int winbase) {
        #pragma unroll
        for (int iss = 0; iss < 2; iss++) {
            int row = 16 * w + 8 * iss + srow8;
            int D = winbase + row;
            int mm = (D <= 1026) ? (D + 1023 > 2048 ? 2048 : D + 1023) : D - 1027;
            lds_dma16(rb + ((size_t)n * 2049 + mm) * 64 + slog * 8,
                      &Rs[(16 * w + 8 * iss) * 64]);
        }
    };

    // BD from staged Rs: 4 i-tiles covering D = [Dbase, Dbase+63]
    auto bd_quad = [&](int Dbase) {
        #pragma unroll
        for (int i = 0; i < 4; i++) {
            const int lr = 16 * i + c;           // Rs row (D - Dbase)
            half8 r0 = *(const half8*)&Rs[lr * 64 + ((g ^ cx) * 8)];
            half8 r1 = *(const half8*)&Rs[lr * 64 + (((4 + g) ^ cx) * 8)];
            const int Dmin = Dbase + 16 * i;
            f32x4 z;
            if (Dmin + 15 <= 1026) {
                f32x4 zm = {};
                zm = __builtin_amdgcn_mfma_f32_16x16x32_f16(r0, av0, zm, 0, 0, 0);
                zm = __builtin_amdgcn_mfma_f32_16x16x32_f16(r1, av1, zm, 0, 0, 0);
                z = zm;
            } else if (Dmin >= 1027) {
                f32x4 zw = {};
                zw = __builtin_amdgcn_mfma_f32_16x16x32_f16(r0, aw0, zw, 0, 0, 0);
                zw = __builtin_amdgcn_mfma_f32_16x16x32_f16(r1, aw1, zw, 0, 0, 0);
                z = zw;
            } else {
                f32x4 zm = {}, zw = {};
                zm = __builtin_amdgcn_mfma_f32_16x16x32_f16(r0, av0, zm, 0, 0, 0);
                zm = __builtin_amdgcn_mfma_f32_16x16x32_f16(r1, av1, zm, 0, 0, 0);
                zw = __builtin_amdgcn_mfma_f32_16x16x32_f16(r0, aw0, zw, 0, 0, 0);
                zw = __builtin_amdgcn_mfma_f32_16x16x32_f16(r1, aw1, zw, 0, 0, 0);
                #pragma unroll
                for (int rg = 0; rg < 4; rg++)
                    z[rg] = (Dmin + 4 * g + rg >= 1027) ? zw[rg] : zm[rg];
            }
            int dz = 1026 - Dmin - 4 * g;                   // zero D==1026
            if (dz >= 0 && dz < 4) z[dz] = 0.f;
            half4 hv;
            #pragma unroll
            for (int rg = 0; rg < 4; rg++) hv[rg] = (_Float16)z[rg];
            int slot0 = (Dmin + 4 * g - d0 + 63) & 127;     // 4-aligned
            _Float16* wp = &BDX[myrow * 132 + slot0];
            *(half4*)wp = hv;
            if (slot0 < 4) *(half4*)(wp + 128) = hv;        // wrap mirror
        }
    };

    // ---- prologue: fill 128-slot BD window; stage tile 0 + r-win 1 ----
    stage_r(d0 - 63);
    __syncthreads();
    bd_quad(d0 - 63);
    __syncthreads();
    stage_r(d0 + 1);
    __syncthreads();
    bd_quad(d0 + 1);
    __syncthreads();
    stage_k(0); stage_v(0); stage_r(d0 + 65);
    __syncthreads();

    for (int kk = 0; kk < 8; kk++) {
        const int diff0 = d0 + kk * 64;

        // ---- S^T = K·Q^T ----
        f32x4 sa[4];
        #pragma unroll
        for (int i = 0; i < 4; i++) {
            const int lr = 16 * i + c;
            bf16x8 kf0 = *(const bf16x8*)&Ks[lr * 64 + ((g ^ cx) * 8)];
            bf16x8 kf1 = *(const bf16x8*)&Ks[lr * 64 + (((4 + g) ^ cx) * 8)];
            f32x4 s = {};
            s = __builtin_amdgcn_mfma_f32_16x16x32_bf16(kf0, qf0, s, 0, 0, 0);
            sa[i] = __builtin_amdgcn_mfma_f32_16x16x32_bf16(kf1, qf1, s, 0, 0, 0);
        }

        // ---- softmax -> packed PV B-operands (no LDS round trip) ----
        bf16x4 pk[4];
        #pragma unroll
        for (int i = 0; i < 4; i++) {
            int slotb = (64 * kk + 16 * i + 4 * g - myrow + 63) & 127;
            half4 bd4 = *(const half4*)&BDX[myrow * 132 + slotb];
            bf16x4 t;
            #pragma unroll
            for (int rg = 0; rg < 4; rg++) {
                float p = exp2f(fmaf(sa[i][rg], C_SCALE, (float)bd4[rg]));
                l_acc += p;
                t[rg] = (short)bf16_rne(p);
            }
            pk[i] = t;
        }

        // ---- BD window advance (MFMA pipe; overlaps softmax/PV) ----
        if (kk < 7) bd_quad(diff0 + 65);

        // ---- O^T += V^T·P^T via k16 MFMA, B from registers ----
        #pragma unroll
        for (int i2 = 0; i2 < 4; i2++) {
            const int vr = 16 * i2 + c;
            #pragma unroll
            for (int i = 0; i < 4; i++) {
                int ch = (2 * i + (g >> 1)) ^ cx;
                bf16x4 vf = *(const bf16x4*)&Vs[vr * 64 + ch * 8 + (g & 1) * 4];
                o[i2] = __builtin_amdgcn_mfma_f32_16x16x16bf16_1k(vf, pk[i], o[i2], 0, 0, 0);
            }
        }

        if (kk < 7) {
            __syncthreads();
            stage_k(kk + 1); stage_v(kk + 1);
            if (kk < 6) stage_r(d0 + 64 * kk + 129);
            __syncthreads();
        }
    }

    // ---- epilogue ----
    float s2 = l_acc;
    s2 += __shfl_xor(s2, 16);
    s2 += __shfl_xor(s2, 32);
    size_t rowb = ((size_t)part * 32 + bn) * 1024 + tg;
    if (g == 0) pl[rowb] = s2;
    float inv = 1.f / s2;
    #pragma unroll
    for (int i2 = 0; i2 < 4; i2++) {
        half4 hv;
        #pragma unroll
        for (int rg = 0; rg < 4; rg++) hv[rg] = (_Float16)(o[i2][rg] * inv);
        *(half4*)&po[rowb * 64 + 16 * i2 + 4 * g] = hv;
    }
}

// ---------------------------------------------------------------------------
// Combine: attn = sum_p l_p * po_p / sum_p l_p
// ---------------------------------------------------------------------------
__global__ __launch_bounds__(256) void combine_kernel(
    const _Float16* __restrict__ po, const float* __restrict__ pl,
    _Float16* __restrict__ attn)
{
    int f = blockIdx.x * 256 + threadIdx.x;
    int h = f & 63, t = (f >> 6) & 1023, bn = f >> 16;
    float os = 0.f, ls = 0.f;
    #pragma unroll
    for (int p = 0; p < 4; p++) {
        size_t rowb = ((size_t)p * 32 + bn) * 1024 + t;
        float lp = pl[rowb];
        os += lp * (float)po[rowb * 64 + h];
        ls += lp;
    }
    int b = bn >> 4, n = bn & 15;
    attn[((size_t)b * 1024 + t) * 1024 + n * 64 + h] = (_Float16)(os / ls);
}

// ---------------------------------------------------------------------------
// Output GEMM, 128x128 tile: out[bt,f] = sum_nh attn[bt,nh]*Woutt[f,nh] + b_out[f]
// ---------------------------------------------------------------------------
__global__ __launch_bounds__(256) void out3_kernel(
    const _Float16* __restrict__ A, const _Float16* __restrict__ Bt,
    const float* __restrict__ bias, float* __restrict__ out)
{
    alignas(16) __shared__ _Float16 As[128 * 64];
    alignas(16) __shared__ _Float16 Bs[128 * 64];
    const int tid = threadIdx.x;
    const int lane = tid & 63, w = tid >> 6, c = lane & 15, g = lane >> 4;
    const int row0 = blockIdx.x * 128, col0 = blockIdx.y * 128;
    const int qr = (w & 1) * 64, qc = (w >> 1) * 64;
    const int srow = lane >> 3, phys = lane & 7;
    f32x4 acc[4][4] = {};

    for (int k0 = 0; k0 < 1024; k0 += 64) {
        #pragma unroll
        for (int q = 0; q < 4; q++) {
            int row = 32 * w + 8 * q + srow;
            int log = phys ^ (row & 7);
            lds_dma16(A  + (size_t)(row0 + row) * 1024 + k0 + log * 8, &As[(32 * w + 8 * q) * 64]);
            lds_dma16(Bt + (size_t)(col0 + row) * 1024 + k0 + log * 8, &Bs[(32 * w + 8 * q) * 64]);
        }
        __syncthreads();
        #pragma unroll
        for (int s = 0; s < 2; s++) {
            half8 af[4], bf[4];
            #pragma unroll
            for (int i = 0; i < 4; i++) {
                int row = qr + 16 * i + c;
                af[i] = *(const half8*)&As[row * 64 + ((4 * s + g) ^ (row & 7)) * 8];
            }
            #pragma unroll
            for (int j = 0; j < 4; j++) {
                int row = qc + 16 * j + c;
                bf[j] = *(const half8*)&Bs[row * 64 + ((4 * s + g) ^ (row & 7)) * 8];
            }
            #pragma unroll
            for (int i = 0; i < 4; i++)
                #pragma unroll
                for (int j = 0; j < 4; j++)
                    acc[i][j] = __builtin_amdgcn_mfma_f32_16x16x32_f16(af[i], bf[j], acc[i][j], 0, 0, 0);
        }
        __syncthreads();
    }
    #pragma unroll
    for (int i = 0; i < 4; i++)
        #pragma unroll
        for (int j = 0; j < 4; j++) {
            const int cg = col0 + qc + 16 * j + c;
            const int rbase = row0 + qr + 16 * i + 4 * g;
            #pragma unroll
            for (int rg = 0; rg < 4; rg++)
                out[(size_t)(rbase + rg) * 1024 + cg] = acc[i][j][rg] + bias[cg];
        }
}

extern "C" void kernel_launch(void* const* d_in, const int* in_sizes, int n_in,
                              void* d_out, int out_size, void* d_ws, size_t ws_size,
                              hipStream_t stream)
{
    const float* x    = (const float*)d_in[0];
    const float* rel  = (const float*)d_in[1];
    const float* mem  = (const float*)d_in[2];
    const float* Wq   = (const float*)d_in[3];
    const float* Wk   = (const float*)d_in[4];
    const float* Wv   = (const float*)d_in[5];
    const float* Wr   = (const float*)d_in[6];
    const float* ub   = (const float*)d_in[7];
    const float* vb   = (const float*)d_in[8];
    const float* Wout = (const float*)d_in[9];
    const float* bout = (const float*)d_in[10];
    float* out = (float*)d_out;

    char* ws = (char*)d_ws;
    unsigned short* qu    = (unsigned short*)(ws);                   // 4 MB   bf16 [B,T,NH]
    _Float16*       qv    = (_Float16*)(ws + (4ull << 20));          // 4 MB   fp16 [B,T,NH] (*C_SCALE)
    unsigned short* kb    = (unsigned short*)(ws + (8ull << 20));    // 8 MB   bf16 [B,S,NH]
    unsigned short* vtb   = (unsigned short*)(ws + (16ull << 20));   // 8 MB   bf16 [B,N,H,S]
    _Float16*       rb    = (_Float16*)(ws + (24ull << 20));         // 4.2 MB fp16 [N,M,H]
    _Float16*       attn  = (_Float16*)(ws + (29ull << 20));         // 4 MB   fp16 [B,T,NH]
    _Float16*       po    = (_Float16*)(ws + (33ull << 20));         // 16.8MB fp16 [4,BN,T,H]
    float*          pl    = (float*)(ws + (50ull << 20));            // 0.5 MB fp32 [4,BN,T]
    _Float16*       x16   = (_Float16*)(ws + (51ull << 20));         // 4 MB
    _Float16*       mem16 = (_Float16*)(ws + (55ull << 20));         // 8 MB
    _Float16*       rel16 = (_Float16*)(ws + (63ull << 20));         // 4.2 MB
    _Float16*       Wqt   = (_Float16*)(ws + (68ull << 20));         // 2 MB each
    _Float16*       Wkt   = (_Float16*)(ws + (70ull << 20));
    _Float16*       Wvt   = (_Float16*)(ws + (72ull << 20));
    _Float16*       Wrt   = (_Float16*)(ws + (74ull << 20));
    _Float16*       Woutt = (_Float16*)(ws + (76ull << 20));

    prep_kernel<<<dim3(5377), 256, 0, stream>>>(
        x, mem, rel, Wq, Wk, Wv, Wr, Wout,
        x16, mem16, rel16, Wqt, Wkt, Wvt, Wrt, Woutt);
    proj3_kernel<<<dim3(97, 8), 256, 0, stream>>>(
        x16, mem16, rel16, Wqt, Wkt, Wvt, Wrt, ub, vb, qu, qv, kb, vtb, rb);
    flash_kernel<<<dim3(2048), 256, 0, stream>>>(qu, qv, kb, vtb, rb, po, pl);
    combine_kernel<<<dim3(8192), 256, 0, stream>>>(po, pl, attn);
    out3_kernel<<<dim3(16, 8), 256, 0, stream>>>(attn, Woutt, bout, out);
}